// Round 12
// baseline (420.953 us; speedup 1.0000x reference)
//
#include <hip/hip_runtime.h>
#include <hip/hip_cooperative_groups.h>
#include <math.h>

namespace cg = cooperative_groups;

#define DET 512
#define NB  16
#define NT  180
#define PI_D 3.14159265358979323846
#define NPAIR 89
#define PADQ 108
#define PKROW 768                // padded packed dwords per (b,tp); [108,620) data
#define NGRP 23                  // ceil(89/4) pair-groups of 4

// ws layout (bytes):
//   [0,712)        trigp float2[89]   symmetric pair trig (c,s)
//   [TT,+512K)     tth[d][k] f16      Toeplitz w[d-k] * 1024
//   [XF0,+32K)     xf0[b][512]  f32   filtered row t=0
//   [XF90,+32K)    xf90[b][512] f32   filtered row t=90
//   [PK,+4.4M)     pkf[b][tp][768] u32  packed (f16 ft[i], f16 fu[i]), pads 0
#define TT_OFF   8192
#define XF0_OFF  (TT_OFF + 512*512*2)
#define XF90_OFF (XF0_OFF + 32768)
#define PK_OFF   (XF90_OFF + 32768)

typedef _Float16 half8  __attribute__((ext_vector_type(8)));
typedef _Float16 half2v __attribute__((ext_vector_type(2)));
typedef float    float4v __attribute__((ext_vector_type(4)));

// f32 acc += f32 w * f16-half(pk)   (VOP3P mix, full-rate)
__device__ inline void fmix_lo(float& acc, float w, unsigned int pk) {
  asm("v_fma_mix_f32 %0, %1, %2, %0 op_sel_hi:[0,1,0]"
      : "+v"(acc) : "v"(w), "v"(pk));
}
__device__ inline void fmix_hi(float& acc, float w, unsigned int pk) {
  asm("v_fma_mix_f32 %0, %1, %2, %0 op_sel:[0,1,0] op_sel_hi:[0,1,0]"
      : "+v"(acc) : "v"(w), "v"(pk));
}

#define SMEM_BYTES 36928   // filter phase: xs_h 16K + xs_l 16K + xfs 4160; backproj: 24576 overlay

__global__ __launch_bounds__(256, 4) void fused_kernel(const float* __restrict__ x,
                                                       char* __restrict__ wsb,
                                                       float* __restrict__ out) {
  __shared__ __align__(16) char smem[SMEM_BYTES];
  int tid = threadIdx.x;
  int bid = blockIdx.x;
  cg::grid_group grid = cg::this_grid();

  // ---------- phase 0: tth table (blocks 0..511) + trig (block 512) ----------
  {
    _Float16* tth = (_Float16*)(wsb + TT_OFF);
    if (bid < 512) {
      int d = bid;
#pragma unroll
      for (int c = 0; c < 2; c++) {
        int k = tid * 2 + c;
        int delta = d - k;
        float w;
        if (delta == 0) w = 0.5f;
        else if (delta & 1) { double dd = (double)delta; w = (float)(-2.0 / (PI_D * PI_D * dd * dd)); }
        else w = 0.f;
        tth[(size_t)d * 512 + k] = (_Float16)(w * 1024.0f);   // scale: avoid f16 denormals
      }
    } else if (bid == 512 && tid < NPAIR) {
      float2* trigp = (float2*)wsb;
      int t = tid + 1, u = 179 - tid;
      float rt = (float)t * (float)(PI_D / 180.0);
      float ru = (float)u * (float)(PI_D / 180.0);
      double ct = cos((double)rt), st = sin((double)rt);
      double cu = cos((double)ru), su = sin((double)ru);
      float2 cs;
      cs.x = (float)((ct - cu) * 0.5);
      cs.y = (float)((st + su) * 0.5);
      trigp[tid] = cs;
    }
  }
  grid.sync();

  // ---------- phase 1: MFMA filter + f16 pair packing (blocks 0..767) ----------
  // p=bid%12, b=(bid/12)%16, z=bid/192; z handles dt in {2z, 2z+1}.
  // Block p<11 angle rows m: m<8 -> t=8p+1+m ; m>=8 -> t=164-8p+m,
  // pair tp=8p+mp in rows (mp,15-mp). Block 11: rows {89,91,0,90} = pair 88 + singles.
  if (bid < 768) {
    _Float16* xs_h = (_Float16*)smem;             // [16][512]
    _Float16* xs_l = (_Float16*)(smem + 16384);   // [16][512]
    float*    xfs  = (float*)(smem + 32768);      // [16][65]
    const _Float16* tth = (const _Float16*)(wsb + TT_OFF);
    unsigned int* pkg = (unsigned int*)(wsb + PK_OFF);

    int p = bid % 12;
    int b = (bid / 12) % 16;
    int z = bid / 192;

    int m = tid & 15, kp = tid >> 4;
    int tS;
    if (p < 11) tS = (m < 8) ? (8 * p + 1 + m) : (164 - 8 * p + m);
    else        tS = (m == 0) ? 89 : ((m == 1) ? 91 : ((m == 3) ? 90 : 0));
    const float* xb = x + (size_t)b * DET * NT + tS;
#pragma unroll 4
    for (int pass = 0; pass < 16; pass++) {
      int k = pass * 32 + kp * 2;
      int c = k >> 3, h = k & 7;
      int phys = (((c ^ (m & 7)) << 3) | h);
      float v0 = xb[(size_t)k * NT];
      float v1 = xb[(size_t)(k + 1) * NT];
      _Float16 h0 = (_Float16)v0, h1 = (_Float16)v1;
      half2v hh = {h0, h1};
      half2v ll = {(_Float16)(v0 - (float)h0), (_Float16)(v1 - (float)h1)};
      *(half2v*)&xs_h[m * 512 + phys] = hh;
      *(half2v*)&xs_l[m * 512 + phys] = ll;
    }
    __syncthreads();

    int nprb = (p < 11) ? 8 : 1;
    int tpb0 = (p < 11) ? 8 * p : 88;
    if (z == 0) {
      int idx = (tid < 108) ? tid : (620 + (tid - 108));   // zero the pads once
      for (int pr = 0; pr < nprb; pr++)
        pkg[((size_t)b * NPAIR + tpb0 + pr) * PKROW + idx] = 0u;
    }

    int lane = tid & 63, wv = tid >> 6;
    int mm = lane & 15, q = lane >> 4;
    const _Float16* arh = &xs_h[mm * 512];
    const _Float16* arl = &xs_l[mm * 512];
    int e = mm & 7;
    int mp = tid >> 5, cc = (tid & 31) * 2;               // pack assignment
    int rT = (p < 11) ? mp : 0;
    int rU = (p < 11) ? (15 - mp) : 1;
    int tpp = (p < 11) ? (8 * p + mp) : 88;
    bool dopack = (p < 11) || (mp == 0);

    for (int dti = 0; dti < 2; dti++) {
      int dt = 2 * z + dti;
      int dw = dt * 64 + wv * 16 + mm;
      const _Float16* th = tth + (size_t)dw * 512;
      float4v acc0 = {0.f, 0.f, 0.f, 0.f};
      float4v acc1 = {0.f, 0.f, 0.f, 0.f};
#pragma unroll 4
      for (int kc = 0; kc < 512; kc += 32) {
        int ph = ((((kc >> 3) + q) ^ e) << 3);
        half8 Ah = *(const half8*)&arh[ph];
        half8 Al = *(const half8*)&arl[ph];
        half8 Bh = *(const half8*)&th[kc + q * 8];
        acc0 = __builtin_amdgcn_mfma_f32_16x16x32_f16(Ah, Bh, acc0, 0, 0, 0);
        acc1 = __builtin_amdgcn_mfma_f32_16x16x32_f16(Al, Bh, acc1, 0, 0, 0);
      }
      if (dti > 0) __syncthreads();      // previous pack finished reading xfs
#pragma unroll
      for (int i = 0; i < 4; i++)
        xfs[(q * 4 + i) * 65 + wv * 16 + mm] = (acc0[i] + acc1[i]) * 0.0009765625f;
      __syncthreads();
      if (dopack) {
        float ft0 = xfs[rT * 65 + cc], ft1 = xfs[rT * 65 + cc + 1];
        float fu0 = xfs[rU * 65 + cc], fu1 = xfs[rU * 65 + cc + 1];
        auto p0 = __builtin_amdgcn_cvt_pkrtz(ft0, fu0);   // lo=ft, hi=fu
        auto p1 = __builtin_amdgcn_cvt_pkrtz(ft1, fu1);
        uint2 dstv;
        __builtin_memcpy(&dstv.x, &p0, 4);
        __builtin_memcpy(&dstv.y, &p1, 4);
        *(uint2*)&pkg[((size_t)b * NPAIR + tpp) * PKROW + PADQ + dt * 64 + cc] = dstv;
      }
      if (p == 11 && tid < 64) {         // singles: row2=t0, row3=t90
        float* f0  = (float*)(wsb + XF0_OFF)  + (size_t)b * DET;
        float* f90 = (float*)(wsb + XF90_OFF) + (size_t)b * DET;
        f0[dt * 64 + tid]  = xfs[2 * 65 + tid];
        f90[dt * 64 + tid] = xfs[3 * 65 + tid];
      }
    }
  }
  grid.sync();

  // ---------- phase 2: backprojection (all 1024 blocks; R11 inner, verified) ----------
  {
    unsigned int* pk = (unsigned int*)smem;   // [2][4][768] overlay = 24576 B
    int b    = bid >> 6;
    int tile = bid & 63;
    int tx   = (tile & 7) * 32;
    int ty   = (tile >> 3) * 32;
    int lx = tid & 31, ly = tid >> 5;

    float* ob = out + (size_t)b * DET * DET;
    int X1 = tx + lx, X2 = 511 - X1;

    int mbx = 449 - 2 * tx, mby = 449 - 2 * ty;
    if (mbx * mbx + mby * mby > 261632) {
#pragma unroll
      for (int j = 0; j < 4; j++) {
        int Y1 = ty + ly + 8 * j, Y2 = 511 - Y1;
        ob[(size_t)Y1 * DET + X1] = 0.f;
        ob[(size_t)Y1 * DET + X2] = 0.f;
        ob[(size_t)Y2 * DET + X2] = 0.f;
        ob[(size_t)Y2 * DET + X1] = 0.f;
      }
      return;
    }

    const float2* trigp = (const float2*)wsb;
    const unsigned int* pkg = (const unsigned int*)(wsb + PK_OFF) + (size_t)b * NPAIR * PKROW;

    int w = tid >> 6, l = tid & 63;

    float p_ = (float)(tx + lx) - 255.5f;
    float q0 = (float)(ty + ly) - 255.5f;

    int mkx = 449 - 2 * tx;
    bool live[4];
#pragma unroll
    for (int j = 0; j < 4; j++) {
      int mky = 509 - 2 * ty - 4 * w - 16 * j;
      live[j] = (mkx * mkx + mky * mky <= 261632);
    }

    float A1[4] = {0,0,0,0}, A2[4] = {0,0,0,0}, A3[4] = {0,0,0,0}, A4[4] = {0,0,0,0};

    auto stage_group = [&](int g, int par) {
      int tp = 4 * g + w;
      if (tp < NPAIR) {
        const unsigned int* src = pkg + (size_t)tp * PKROW + l * 4;
        char* dst = (char*)(pk + (par * 4 + w) * PKROW);
#pragma unroll
        for (int c3 = 0; c3 < 3; c3++)
          __builtin_amdgcn_global_load_lds(
              (const __attribute__((address_space(1))) unsigned int*)(src + c3 * 256),
              (__attribute__((address_space(3))) unsigned int*)(dst + c3 * 1024),
              16, 0, 0);
      }
    };

    stage_group(0, 0);
    __syncthreads();

    for (int g = 0; g < NGRP; g++) {
      if (g + 1 < NGRP) stage_group(g + 1, (g + 1) & 1);
      int npair = (g < NGRP - 1) ? 4 : (NPAIR - 4 * (NGRP - 1));
      for (int cgi = 0; cgi < npair; cgi++) {
        int tp = 4 * g + cgi;
        float2 cs = trigp[tp];
        float c = cs.x, s = cs.y;
        const unsigned int* col = pk + ((g & 1) * 4 + cgi) * PKROW;
        float inner = fmaf(-s, q0, 255.5f + (float)PADQ);
        float iyA = fmaf( c, p_, inner);
        float iyB = fmaf(-c, p_, inner);
        float s8 = 8.f * s;
#pragma unroll
        for (int j = 0; j < 4; j++) {
          if (live[j]) {
            int   iA = (int)iyA;          // iy in [2,725] -> trunc == floor
            float wA = iyA - (float)iA;
            int   iB = (int)iyB;
            float wB = iyB - (float)iB;
            float vA = 1.f - wA, vB = 1.f - wB;
            uint2 dA, dB, dMA, dMB;       // (pk[i], pk[i+1]) -> ds_read2_b32
            __builtin_memcpy(&dA,  &col[iA], 8);
            __builtin_memcpy(&dB,  &col[iB], 8);
            __builtin_memcpy(&dMA, &col[726 - iA], 8);
            __builtin_memcpy(&dMB, &col[726 - iB], 8);
            fmix_lo(A1[j], vA, dA.x);  fmix_lo(A1[j], wA, dA.y);
            fmix_hi(A1[j], vB, dB.x);  fmix_hi(A1[j], wB, dB.y);
            fmix_lo(A2[j], vB, dB.x);  fmix_lo(A2[j], wB, dB.y);
            fmix_hi(A2[j], vA, dA.x);  fmix_hi(A2[j], wA, dA.y);
            fmix_lo(A3[j], wA, dMA.x); fmix_lo(A3[j], vA, dMA.y);
            fmix_hi(A3[j], wB, dMB.x); fmix_hi(A3[j], vB, dMB.y);
            fmix_lo(A4[j], wB, dMB.x); fmix_lo(A4[j], vB, dMB.y);
            fmix_hi(A4[j], wA, dMA.x); fmix_hi(A4[j], vA, dMA.y);
          }
          iyA -= s8; iyB -= s8;
        }
      }
      __syncthreads();
    }

    const float* f0  = (const float*)(wsb + XF0_OFF)  + (size_t)b * DET;
    const float* f90 = (const float*)(wsb + XF90_OFF) + (size_t)b * DET;
    float g0a = f0[X1], g0b = f0[X2];
    int kx = 2 * X1 - 511;
    const float SC = (float)(PI_D / 360.0);
#pragma unroll
    for (int j = 0; j < 4; j++) {
      int Y1 = ty + ly + 8 * j, Y2 = 511 - Y1;
      float g90a = f90[Y2];
      float g90b = f90[Y1];
      int ky = 2 * Y1 - 511;
      bool in = (kx * kx + ky * ky) <= 261632;
      float P1 = A1[j] + g0a + g90a;
      float P2 = A2[j] + g0b + g90a;
      float P3 = A3[j] + g0b + g90b;
      float P4 = A4[j] + g0a + g90b;
      ob[(size_t)Y1 * DET + X1] = in ? P1 * SC : 0.f;
      ob[(size_t)Y1 * DET + X2] = in ? P2 * SC : 0.f;
      ob[(size_t)Y2 * DET + X2] = in ? P3 * SC : 0.f;
      ob[(size_t)Y2 * DET + X1] = in ? P4 * SC : 0.f;
    }
  }
}

extern "C" void kernel_launch(void* const* d_in, const int* in_sizes, int n_in,
                              void* d_out, int out_size, void* d_ws, size_t ws_size,
                              hipStream_t stream) {
  (void)in_sizes; (void)n_in; (void)out_size; (void)ws_size;
  const float* x = (const float*)d_in[0];
  float* out = (float*)d_out;
  char*  wsb = (char*)d_ws;

  void* args[] = {(void*)&x, (void*)&wsb, (void*)&out};
  hipLaunchCooperativeKernel((void*)fused_kernel, dim3(1024), dim3(256),
                             args, 0, stream);
}

// Round 13
// 180.314 us; speedup vs baseline: 2.3346x; 2.3346x over previous
//
#include <hip/hip_runtime.h>
#include <math.h>

#define DET 512
#define NB  16
#define NT  180
#define PI_D 3.14159265358979323846
#define NPAIR 89
#define PADQ 108
#define PKROW 768                // padded packed dwords per (b,tp); [108,620) data
#define NGRP3 30                 // ceil(89/3) pair-groups of 3

// ws layout (bytes):
//   [0,712)        trigp float2[89]   symmetric pair trig (c,s)
//   [TT,+512K)     tth[d][k] f16      Toeplitz w[d-k] * 1024
//   [XF0,+32K)     xf0[b][512]  f32   filtered row t=0
//   [XF90,+32K)    xf90[b][512] f32   filtered row t=90
//   [PK,+4.4M)     pkf[b][tp][768] u32  packed (f16 ft[i], f16 fu[i]), pads 0
#define TT_OFF   8192
#define XF0_OFF  (TT_OFF + 512*512*2)
#define XF90_OFF (XF0_OFF + 32768)
#define PK_OFF   (XF90_OFF + 32768)

typedef _Float16 half8  __attribute__((ext_vector_type(8)));
typedef _Float16 half2v __attribute__((ext_vector_type(2)));
typedef float    float4v __attribute__((ext_vector_type(4)));

// f32 acc += f32 w * f16-half(pk)   (VOP3P mix, full-rate)
__device__ inline void fmix_lo(float& acc, float w, unsigned int pk) {
  asm("v_fma_mix_f32 %0, %1, %2, %0 op_sel_hi:[0,1,0]"
      : "+v"(acc) : "v"(w), "v"(pk));
}
__device__ inline void fmix_hi(float& acc, float w, unsigned int pk) {
  asm("v_fma_mix_f32 %0, %1, %2, %0 op_sel:[0,1,0] op_sel_hi:[0,1,0]"
      : "+v"(acc) : "v"(w), "v"(pk));
}

// ---------------- init: trig + scaled f16 Toeplitz table ----------------
__global__ __launch_bounds__(256) void init_kernel(char* __restrict__ wsb) {
  int tid = threadIdx.x;
  int d = blockIdx.x;
  _Float16* tth = (_Float16*)(wsb + TT_OFF);
#pragma unroll
  for (int c = 0; c < 2; c++) {
    int k = tid * 2 + c;
    int delta = d - k;
    float w;
    if (delta == 0) w = 0.5f;
    else if (delta & 1) { double dd = (double)delta; w = (float)(-2.0 / (PI_D * PI_D * dd * dd)); }
    else w = 0.f;
    tth[(size_t)d * 512 + k] = (_Float16)(w * 1024.0f);   // scale: avoid f16 denormals
  }
  if (d == 0 && tid < NPAIR) {
    float2* trigp = (float2*)wsb;
    int t = tid + 1, u = 179 - tid;
    float rt = (float)t * (float)(PI_D / 180.0);
    float ru = (float)u * (float)(PI_D / 180.0);
    double ct = cos((double)rt), st = sin((double)rt);
    double cu = cos((double)ru), su = sin((double)ru);
    float2 cs;
    cs.x = (float)((ct - cu) * 0.5);
    cs.y = (float)((st + su) * 0.5);
    trigp[tid] = cs;
  }
}

// ---------------- Filter (MFMA GEMM) + fused f16 pair-packing (R11, unchanged) ----------------
__global__ __launch_bounds__(256) void filter_kernel(const float* __restrict__ x,
                                                     char* __restrict__ wsb) {
  __shared__ _Float16 xs_h[16][512];
  __shared__ _Float16 xs_l[16][512];
  __shared__ float xfs[16][65];
  const _Float16* tth = (const _Float16*)(wsb + TT_OFF);
  unsigned int* pkg = (unsigned int*)(wsb + PK_OFF);

  int tid = threadIdx.x;
  int p = blockIdx.x, b = blockIdx.y;
  int dt0 = blockIdx.z * 4;

  int m = tid & 15, kp = tid >> 4;
  int tS;
  if (p < 11) tS = (m < 8) ? (8 * p + 1 + m) : (164 - 8 * p + m);
  else        tS = (m == 0) ? 89 : ((m == 1) ? 91 : ((m == 3) ? 90 : 0));
  const float* xb = x + (size_t)b * DET * NT + tS;
#pragma unroll 4
  for (int pass = 0; pass < 16; pass++) {
    int k = pass * 32 + kp * 2;
    int c = k >> 3, h = k & 7;
    int phys = (((c ^ (m & 7)) << 3) | h);
    float v0 = xb[(size_t)k * NT];
    float v1 = xb[(size_t)(k + 1) * NT];
    _Float16 h0 = (_Float16)v0, h1 = (_Float16)v1;
    half2v hh = {h0, h1};
    half2v ll = {(_Float16)(v0 - (float)h0), (_Float16)(v1 - (float)h1)};
    *(half2v*)&xs_h[m][phys] = hh;
    *(half2v*)&xs_l[m][phys] = ll;
  }
  __syncthreads();

  int nprb = (p < 11) ? 8 : 1;
  int tpb0 = (p < 11) ? 8 * p : 88;
  if (blockIdx.z == 0) {
    int idx = (tid < 108) ? tid : (620 + (tid - 108));   // zero pads once
    for (int pr = 0; pr < nprb; pr++)
      pkg[((size_t)b * NPAIR + tpb0 + pr) * PKROW + idx] = 0u;
  }

  int lane = tid & 63, wv = tid >> 6;
  int mm = lane & 15, q = lane >> 4;
  const _Float16* arh = &xs_h[mm][0];
  const _Float16* arl = &xs_l[mm][0];
  int e = mm & 7;
  int mp = tid >> 5, cc = (tid & 31) * 2;
  int rT = (p < 11) ? mp : 0;
  int rU = (p < 11) ? (15 - mp) : 1;
  int tpp = (p < 11) ? (8 * p + mp) : 88;
  bool dopack = (p < 11) || (mp == 0);

  for (int dti = 0; dti < 4; dti++) {
    int dt = dt0 + dti;
    int dw = dt * 64 + wv * 16 + mm;
    const _Float16* th = tth + (size_t)dw * 512;
    float4v acc0 = {0.f, 0.f, 0.f, 0.f};
    float4v acc1 = {0.f, 0.f, 0.f, 0.f};
#pragma unroll 4
    for (int kc = 0; kc < 512; kc += 32) {
      int ph = ((((kc >> 3) + q) ^ e) << 3);
      half8 Ah = *(const half8*)&arh[ph];
      half8 Al = *(const half8*)&arl[ph];
      half8 Bh = *(const half8*)&th[kc + q * 8];
      acc0 = __builtin_amdgcn_mfma_f32_16x16x32_f16(Ah, Bh, acc0, 0, 0, 0);
      acc1 = __builtin_amdgcn_mfma_f32_16x16x32_f16(Al, Bh, acc1, 0, 0, 0);
    }
    if (dti > 0) __syncthreads();
#pragma unroll
    for (int i = 0; i < 4; i++)
      xfs[q * 4 + i][wv * 16 + mm] = (acc0[i] + acc1[i]) * 0.0009765625f;
    __syncthreads();
    if (dopack) {
      float ft0 = xfs[rT][cc], ft1 = xfs[rT][cc + 1];
      float fu0 = xfs[rU][cc], fu1 = xfs[rU][cc + 1];
      auto p0 = __builtin_amdgcn_cvt_pkrtz(ft0, fu0);   // lo=ft, hi=fu
      auto p1 = __builtin_amdgcn_cvt_pkrtz(ft1, fu1);
      uint2 dstv;
      __builtin_memcpy(&dstv.x, &p0, 4);
      __builtin_memcpy(&dstv.y, &p1, 4);
      *(uint2*)&pkg[((size_t)b * NPAIR + tpp) * PKROW + PADQ + dt * 64 + cc] = dstv;
    }
    if (p == 11 && tid < 64) {         // singles: row2=t0, row3=t90
      float* f0  = (float*)(wsb + XF0_OFF)  + (size_t)b * DET;
      float* f90 = (float*)(wsb + XF90_OFF) + (size_t)b * DET;
      f0[dt * 64 + tid]  = xfs[2][tid];
      f90[dt * 64 + tid] = xfs[3][tid];
    }
  }
}

// ---------------- Backprojection v8: 32x16 tiles, 8 blocks/CU ----------------
// Grid (128,16): tile = bid.x -> tx=(tile&7)*32, ty=(tile>>3)*16. 2 j-rows/thread.
// Groups of 3 pairs, double-buffered: LDS 18.4 KB -> 8 blocks/CU co-resident.
__global__ __launch_bounds__(256, 8) void backproj_kernel(
    const char* __restrict__ wsb, float* __restrict__ out) {
  __shared__ unsigned int pk[2][3][PKROW];   // 18432 B
  int tid = threadIdx.x;
  int b   = blockIdx.y;
  int tx  = (blockIdx.x & 7) * 32;
  int ty  = (blockIdx.x >> 3) * 16;
  int lx = tid & 31, ly = tid >> 5;

  float* ob = out + (size_t)b * DET * DET;
  int X1 = tx + lx, X2 = 511 - X1;

  // block-level skip: tile (and its 3 mirrors) fully outside the circle
  int mbx = 449 - 2 * tx, mby = 481 - 2 * ty;
  if (mbx * mbx + mby * mby > 261632) {
#pragma unroll
    for (int j = 0; j < 2; j++) {
      int Y1 = ty + ly + 8 * j, Y2 = 511 - Y1;
      ob[(size_t)Y1 * DET + X1] = 0.f;
      ob[(size_t)Y1 * DET + X2] = 0.f;
      ob[(size_t)Y2 * DET + X2] = 0.f;
      ob[(size_t)Y2 * DET + X1] = 0.f;
    }
    return;
  }

  const float2* trigp = (const float2*)wsb;
  const unsigned int* pkg = (const unsigned int*)(wsb + PK_OFF) + (size_t)b * NPAIR * PKROW;

  int w = tid >> 6, l = tid & 63;

  float p_ = (float)(tx + lx) - 255.5f;
  float q0 = (float)(ty + ly) - 255.5f;

  int mkx = 449 - 2 * tx;
  bool live[2];
#pragma unroll
  for (int j = 0; j < 2; j++) {
    int mky = 509 - 2 * ty - 4 * w - 16 * j;
    live[j] = (mkx * mkx + mky * mky <= 261632);
  }

  float A1[2] = {0,0}, A2[2] = {0,0}, A3[2] = {0,0}, A4[2] = {0,0};

  // wave w<3 stages column tp=3g+w (3x 16B-wide DMA = 3072 B)
  auto stage_group = [&](int g, int par) {
    int tp = 3 * g + w;
    if (w < 3 && tp < NPAIR) {
      const unsigned int* src = pkg + (size_t)tp * PKROW + l * 4;
      char* dst = (char*)&pk[par][w][0];
#pragma unroll
      for (int c3 = 0; c3 < 3; c3++)
        __builtin_amdgcn_global_load_lds(
            (const __attribute__((address_space(1))) unsigned int*)(src + c3 * 256),
            (__attribute__((address_space(3))) unsigned int*)(dst + c3 * 1024),
            16, 0, 0);
    }
  };

  stage_group(0, 0);
  __syncthreads();

  for (int g = 0; g < NGRP3; g++) {
    if (g + 1 < NGRP3) stage_group(g + 1, (g + 1) & 1);
    int npair = (g < NGRP3 - 1) ? 3 : (NPAIR - 3 * (NGRP3 - 1));
    for (int cgi = 0; cgi < npair; cgi++) {
      int tp = 3 * g + cgi;
      float2 cs = trigp[tp];
      float c = cs.x, s = cs.y;
      const unsigned int* col = &pk[g & 1][cgi][0];
      float inner = fmaf(-s, q0, 255.5f + (float)PADQ);
      float iyA = fmaf( c, p_, inner);
      float iyB = fmaf(-c, p_, inner);
      float s8 = 8.f * s;
#pragma unroll
      for (int j = 0; j < 2; j++) {
        if (live[j]) {
          int   iA = (int)iyA;          // iy in [2,725] -> trunc == floor
          float wA = iyA - (float)iA;
          int   iB = (int)iyB;
          float wB = iyB - (float)iB;
          float vA = 1.f - wA, vB = 1.f - wB;
          uint2 dA, dB, dMA, dMB;       // (pk[i], pk[i+1]) -> ds_read2_b32
          __builtin_memcpy(&dA,  &col[iA], 8);
          __builtin_memcpy(&dB,  &col[iB], 8);
          __builtin_memcpy(&dMA, &col[726 - iA], 8);
          __builtin_memcpy(&dMB, &col[726 - iB], 8);
          // P1: vA*ft[iA] + wA*ft[iA+1] + vB*fu[iB] + wB*fu[iB+1]
          fmix_lo(A1[j], vA, dA.x);  fmix_lo(A1[j], wA, dA.y);
          fmix_hi(A1[j], vB, dB.x);  fmix_hi(A1[j], wB, dB.y);
          // P2: vB*ft[iB] + wB*ft[iB+1] + vA*fu[iA] + wA*fu[iA+1]
          fmix_lo(A2[j], vB, dB.x);  fmix_lo(A2[j], wB, dB.y);
          fmix_hi(A2[j], vA, dA.x);  fmix_hi(A2[j], wA, dA.y);
          // P3: wA*ft[726-iA] + vA*ft[727-iA] + wB*fu[726-iB] + vB*fu[727-iB]
          fmix_lo(A3[j], wA, dMA.x); fmix_lo(A3[j], vA, dMA.y);
          fmix_hi(A3[j], wB, dMB.x); fmix_hi(A3[j], vB, dMB.y);
          // P4: wB*ft[726-iB] + vB*ft[727-iB] + wA*fu[726-iA] + vA*fu[727-iA]
          fmix_lo(A4[j], wB, dMB.x); fmix_lo(A4[j], vB, dMB.y);
          fmix_hi(A4[j], wA, dMA.x); fmix_hi(A4[j], vA, dMA.y);
        }
        iyA -= s8; iyB -= s8;
      }
    }
    __syncthreads();
  }

  // singles t=0 (iy=X exactly) and t=90 (iy~=511-Y), mask, scale
  const float* f0  = (const float*)(wsb + XF0_OFF)  + (size_t)b * DET;
  const float* f90 = (const float*)(wsb + XF90_OFF) + (size_t)b * DET;
  float g0a = f0[X1], g0b = f0[X2];
  int kx = 2 * X1 - 511;
  const float SC = (float)(PI_D / 360.0);
#pragma unroll
  for (int j = 0; j < 2; j++) {
    int Y1 = ty + ly + 8 * j, Y2 = 511 - Y1;
    float g90a = f90[Y2];
    float g90b = f90[Y1];
    int ky = 2 * Y1 - 511;
    bool in = (kx * kx + ky * ky) <= 261632;
    float P1 = A1[j] + g0a + g90a;
    float P2 = A2[j] + g0b + g90a;
    float P3 = A3[j] + g0b + g90b;
    float P4 = A4[j] + g0a + g90b;
    ob[(size_t)Y1 * DET + X1] = in ? P1 * SC : 0.f;
    ob[(size_t)Y1 * DET + X2] = in ? P2 * SC : 0.f;
    ob[(size_t)Y2 * DET + X2] = in ? P3 * SC : 0.f;
    ob[(size_t)Y2 * DET + X1] = in ? P4 * SC : 0.f;
  }
}

extern "C" void kernel_launch(void* const* d_in, const int* in_sizes, int n_in,
                              void* d_out, int out_size, void* d_ws, size_t ws_size,
                              hipStream_t stream) {
  (void)in_sizes; (void)n_in; (void)out_size; (void)ws_size;
  const float* x = (const float*)d_in[0];
  float* out = (float*)d_out;
  char*  wsb = (char*)d_ws;

  init_kernel<<<512, 256, 0, stream>>>(wsb);
  filter_kernel<<<dim3(12, 16, 2), 256, 0, stream>>>(x, wsb);
  backproj_kernel<<<dim3(128, 16), 256, 0, stream>>>(wsb, out);
}